// Round 18
// baseline (868.047 us; speedup 1.0000x reference)
//
#include <hip/hip_runtime.h>
#include <stdint.h>

// ---------------- types & helpers ----------------
typedef __bf16 v8bf __attribute__((ext_vector_type(8)));
typedef float  v4f  __attribute__((ext_vector_type(4)));

__device__ __forceinline__ float bf2f(uint16_t h) {
    union { uint32_t u; float f; } x; x.u = ((uint32_t)h) << 16; return x.f;
}
__device__ __forceinline__ uint16_t f2bf(float f) {
    union { float f; uint32_t u; } x; x.f = f;
    uint32_t r = x.u + 0x7fffu + ((x.u >> 16) & 1u);
    return (uint16_t)(r >> 16);
}

__device__ __forceinline__ void gload16(const uint16_t* g, uint16_t* l) {
    __builtin_amdgcn_global_load_lds((const __attribute__((address_space(1))) void*)g,
                                     (__attribute__((address_space(3))) void*)l, 16, 0, 0);
}

// ---------------- embed ----------------
__global__ void k_embed(const int* __restrict__ x, const float* __restrict__ tok,
                        const float* __restrict__ pos, float* __restrict__ hf,
                        uint16_t* __restrict__ hb)
{
    int i = blockIdx.x;
    int t = i & 1023;
    int tk = x[i];
    const float* te = tok + (long)tk * 768;
    const float* pe = pos + (long)t * 768;
    for (int j = threadIdx.x; j < 768; j += 256) {
        float v = te[j] + pe[j];
        hf[(long)i * 768 + j] = v;
        hb[(long)i * 768 + j] = f2bf(v);
    }
}

// ---------------- transpose + cast to bf16 ----------------
template<typename SrcT>
__global__ void k_transpose(const SrcT* __restrict__ src, uint16_t* __restrict__ dst,
                            int ldS, int ldD, long sBatch, long dBatch)
{
    __shared__ float tile[32][33];
    src += (long)blockIdx.z * sBatch;
    dst += (long)blockIdx.z * dBatch;
    int c0 = blockIdx.x * 32, r0 = blockIdx.y * 32;
    int tx = threadIdx.x, ty = threadIdx.y;
    #pragma unroll
    for (int i = 0; i < 4; ++i) {
        int r = r0 + ty + i * 8;
        SrcT s = src[(long)r * ldS + c0 + tx];
        float v;
        if constexpr (sizeof(SrcT) == 4) v = (float)s; else v = bf2f((uint16_t)s);
        tile[ty + i * 8][tx] = v;
    }
    __syncthreads();
    #pragma unroll
    for (int i = 0; i < 4; ++i) {
        int c = c0 + ty + i * 8;
        dst[(long)c * ldD + r0 + tx] = f2bf(tile[tx][ty + i * 8]);
    }
}

// ---------------- concat qkv biases: grid (3, L) ----------------
__global__ void k_concat3(const float* __restrict__ a, const float* __restrict__ b,
                          const float* __restrict__ c, float* __restrict__ out)
{
    int l = blockIdx.y;
    const float* s = (blockIdx.x == 0) ? a : ((blockIdx.x == 1) ? b : c);
    s += (long)l * 768;
    for (int j = threadIdx.x; j < 768; j += 256)
        out[(long)l * 2304 + blockIdx.x * 768 + j] = s[j];
}

// ==== layer GEMM: 128x64 tile, BK=64, SINGLE 24 KB buffer, 6 blocks/CU (R18) ====
// R18 change: drop ring-2 dbuf; protocol = { stage(kti) -> vmcnt(0) -> barrier ->
// compute -> barrier } (R11/R15-verified). LDS 24 KB -> 6 blocks/CU = 24 waves/CU;
// cross-block wave overlap (m114) hides the serial stage that ring-2 at 3 blocks/CU
// only half-hid. Swizzle + VOUT fusion unchanged (R9/R17-verified).
template<typename OutT, bool BIAS, bool RELU, bool RES, bool VOUT>
__global__ __launch_bounds__(256, 6)
void k_gemmp(const uint16_t* __restrict__ A, const uint16_t* __restrict__ BT,
             OutT* __restrict__ C, const float* __restrict__ bias,
             const float* __restrict__ res, uint16_t* __restrict__ vout,
             int K, int lda, int ldb, int ldc,
             long bsA, long bsB, long bsC, float scale, int causal)
{
    const int nwg = gridDim.x * gridDim.y;
    int lin = blockIdx.y * gridDim.x + blockIdx.x;
    {
        int q = nwg >> 3, r = nwg & 7, x = lin & 7, i = lin >> 3;
        lin = (x < r ? x * (q + 1) : r * (q + 1) + (x - r) * q) + i;
    }
    const int mt = lin % gridDim.y;
    const int nt = lin / gridDim.y;

    if (causal == 1 && nt * 64 >= (mt + 1) * 128) return;
    const int Keff = (causal == 2) ? ((mt + 1) * 128 < K ? (mt + 1) * 128 : K) : K;
    const int KT = Keff >> 6;

    __shared__ uint16_t lds[192 * 64];   // 24 KiB: A rows 0..127, B rows 128..191
    const int tid  = threadIdx.x;
    const int lane = tid & 63;
    const int bz   = blockIdx.z;
    const uint16_t* Ab = A + (long)bz * bsA + (long)mt * 128 * lda;
    const uint16_t* Bb = BT + (long)bz * bsB + (long)nt * 64 * ldb;

    const int wm = (tid >> 6) >> 1, wn = (tid >> 6) & 1;
    const int fr = lane & 15, fq = lane >> 4;

    const int srow = tid >> 3;
    const int sl   = tid & 7;

    v4f acc[4][2];
    #pragma unroll
    for (int m = 0; m < 4; ++m)
        #pragma unroll
        for (int n = 0; n < 2; ++n) acc[m][n] = (v4f){0.f, 0.f, 0.f, 0.f};

    for (int kti = 0; kti < KT; ++kti) {
        const int ko = kti * 64;
        #pragma unroll
        for (int p = 0; p < 6; ++p) {
            int row = p * 32 + srow;
            int ss  = (sl ^ (row & 7)) * 8;
            const uint16_t* g = (p < 4) ? (Ab + (long)row * lda + ko + ss)
                                        : (Bb + (long)(row - 128) * ldb + ko + ss);
            gload16(g, &lds[p * 2048 + tid * 8]);
        }
        asm volatile("s_waitcnt vmcnt(0)" ::: "memory");
        __builtin_amdgcn_s_barrier();

        #pragma unroll
        for (int kk = 0; kk < 2; ++kk) {
            const int sIdx = kk * 4 + fq;
            v8bf ag[4], bg[2];
            #pragma unroll
            for (int m = 0; m < 4; ++m) {
                int r = wm * 64 + m * 16 + fr;
                ag[m] = *(const v8bf*)&lds[r * 64 + ((sIdx ^ (r & 7)) << 3)];
            }
            #pragma unroll
            for (int n = 0; n < 2; ++n) {
                int r = 128 + wn * 32 + n * 16 + fr;
                bg[n] = *(const v8bf*)&lds[r * 64 + ((sIdx ^ (r & 7)) << 3)];
            }
            __builtin_amdgcn_s_setprio(1);
            #pragma unroll
            for (int m = 0; m < 4; ++m)
                #pragma unroll
                for (int n = 0; n < 2; ++n)
                    acc[m][n] = __builtin_amdgcn_mfma_f32_16x16x32_bf16(ag[m], bg[n], acc[m][n], 0, 0, 0);
            __builtin_amdgcn_s_setprio(0);
        }
        __builtin_amdgcn_s_barrier();   // WAR: readers done before next stage
    }

    if (VOUT && nt >= 24) {
        // V region of qkv: write transposed to vout[b][d][s]; b=row>>10, s=row&1023
        #pragma unroll
        for (int n = 0; n < 2; ++n) {
            int col = wn * 32 + n * 16 + fr;
            float bv = BIAS ? bias[nt * 64 + col] : 0.f;
            int d = nt * 64 + col - 1536;      // 0..767
            #pragma unroll
            for (int m = 0; m < 4; ++m) {
                int grow = mt * 128 + wm * 64 + m * 16 + fq * 4;   // multiple of 4
                union { uint16_t u[4]; unsigned long long ll; } t4;
                #pragma unroll
                for (int r = 0; r < 4; ++r) t4.u[r] = f2bf(acc[m][n][r] * scale + bv);
                *(unsigned long long*)&vout[((long)(grow >> 10) * 768 + d) * 1024 + (grow & 1023)] = t4.ll;
            }
        }
        return;
    }

    OutT* Cb = C + (long)bz * bsC + (long)mt * 128 * ldc + nt * 64;
    const float* Rb = RES ? (res + (long)bz * bsC + (long)mt * 128 * ldc + nt * 64) : nullptr;
    #pragma unroll
    for (int n = 0; n < 2; ++n) {
        int col = wn * 32 + n * 16 + fr;
        float bv = BIAS ? bias[nt * 64 + col] : 0.f;
        #pragma unroll
        for (int m = 0; m < 4; ++m) {
            #pragma unroll
            for (int r = 0; r < 4; ++r) {
                int row = wm * 64 + m * 16 + fq * 4 + r;
                float v = acc[m][n][r] * scale + bv;
                if (RES) v += Rb[(long)row * ldc + col];
                if (RELU) v = fmaxf(v, 0.f);
                if constexpr (sizeof(OutT) == 4) Cb[(long)row * ldc + col] = v;
                else                             Cb[(long)row * ldc + col] = f2bf(v);
            }
        }
    }
}

// ==== logits GEMM: 256x256, BK=64, 8-phase counted-vmcnt (R16, verified) ====
#define STAGE_H(buf, op, half, s)                                                   \
    do { if ((s) < KS) {                                                            \
        const uint16_t* Gp_ = (op) ? Bb : Ab;                                       \
        const int ldg_ = (op) ? ldb : lda;                                          \
        uint16_t* dst_ = &lds[buf][(op) * 16384 + (half) * 8192];                   \
        { int rg_ = (half) * 128 + (tid >> 3);                                      \
          int ss_ = ((tid & 7) ^ (rg_ & 7)) << 3;                                   \
          gload16(Gp_ + (long)rg_ * ldg_ + (s) * 64 + ss_, dst_ + tid * 8); }       \
        { int rg_ = (half) * 128 + (tid >> 3) + 64;                                 \
          int ss_ = ((tid & 7) ^ (rg_ & 7)) << 3;                                   \
          gload16(Gp_ + (long)rg_ * ldg_ + (s) * 64 + ss_, dst_ + (tid + 512) * 8); } \
    } } while (0)

#define READ_AG(buf, mh)                                                            \
    do { _Pragma("unroll") for (int m_ = 0; m_ < 4; ++m_) {                         \
        int r_ = wm * 128 + (mh) * 64 + m_ * 16 + fr;                               \
        ag[m_][0] = *(const v8bf*)&lds[buf][r_ * 64 + ((fq ^ (r_ & 7)) << 3)];      \
        ag[m_][1] = *(const v8bf*)&lds[buf][r_ * 64 + (((4 | fq) ^ (r_ & 7)) << 3)];\
    } } while (0)

#define READ_BG(buf, nh, BG)                                                        \
    do { _Pragma("unroll") for (int n_ = 0; n_ < 2; ++n_) {                         \
        int r_ = wn * 64 + (nh) * 32 + n_ * 16 + fr;                                \
        BG[n_][0] = *(const v8bf*)&lds[buf][16384 + r_ * 64 + ((fq ^ (r_ & 7)) << 3)]; \
        BG[n_][1] = *(const v8bf*)&lds[buf][16384 + r_ * 64 + (((4 | fq) ^ (r_ & 7)) << 3)]; \
    } } while (0)

#define MMAQ(mh, nh, BG)                                                            \
    do { __builtin_amdgcn_s_setprio(1);                                             \
        _Pragma("unroll") for (int m_ = 0; m_ < 4; ++m_)                            \
        _Pragma("unroll") for (int n_ = 0; n_ < 2; ++n_) {                          \
            acc[(mh)*4+m_][(nh)*2+n_] = __builtin_amdgcn_mfma_f32_16x16x32_bf16(    \
                ag[m_][0], BG[n_][0], acc[(mh)*4+m_][(nh)*2+n_], 0, 0, 0);          \
            acc[(mh)*4+m_][(nh)*2+n_] = __builtin_amdgcn_mfma_f32_16x16x32_bf16(    \
                ag[m_][1], BG[n_][1], acc[(mh)*4+m_][(nh)*2+n_], 0, 0, 0);          \
        }                                                                           \
        __builtin_amdgcn_s_setprio(0);                                              \
    } while (0)

__global__ __launch_bounds__(512, 2)
void k_glogits(const uint16_t* __restrict__ A, const uint16_t* __restrict__ BT,
               float* __restrict__ C, const float* __restrict__ bias,
               int K, int lda, int ldb, int ldc, float scale)
{
    __shared__ uint16_t lds[2][32768];   // [buf][A 256x64 | B 256x64] = 128 KiB

    const int nwg = gridDim.x * gridDim.y;
    int lin = blockIdx.y * gridDim.x + blockIdx.x;
    {
        int q = nwg >> 3, r = nwg & 7, x = lin & 7, i = lin >> 3;
        lin = (x < r ? x * (q + 1) : r * (q + 1) + (x - r) * q) + i;
    }
    const int nt = lin % gridDim.x;   // 125 n-tiles (n-fastest within XCD chunk)
    const int mt = lin / gridDim.x;   // 8 m-bands (one per XCD chunk)

    const int tid  = threadIdx.x;
    const int lane = tid & 63;
    const int wid  = tid >> 6;
    const int wm = wid >> 2, wn = wid & 3;       // 2M x 4N -> 128x64 per wave
    const int fr = lane & 15, fq = lane >> 4;

    const uint16_t* Ab = A  + (long)mt * 256 * lda;
    const uint16_t* Bb = BT + (long)nt * 256 * ldb;

    const int KS  = K >> 6;        // 12 K-steps
    const int NIT = KS >> 1;       // 6 iterations

    v4f acc[8][4];
    #pragma unroll
    for (int m = 0; m < 8; ++m)
        #pragma unroll
        for (int n = 0; n < 4; ++n) acc[m][n] = (v4f){0.f, 0.f, 0.f, 0.f};

    v8bf ag[4][2], bg0[2][2], bg1[2][2];

    STAGE_H(0, 0, 0, 0);
    STAGE_H(0, 0, 1, 0);
    STAGE_H(0, 1, 0, 0);
    STAGE_H(0, 1, 1, 0);
    STAGE_H(1, 0, 0, 1);

    for (int i = 0; i < NIT; ++i) {
        const int s1 = 2 * i + 1;
        asm volatile("s_waitcnt vmcnt(2)" ::: "memory");
        __builtin_amdgcn_s_barrier();
        READ_AG(0, 0); READ_BG(0, 0, bg0);
        STAGE_H(1, 0, 1, s1);
        MMAQ(0, 0, bg0);
        __builtin_amdgcn_s_barrier();
        READ_BG(0, 1, bg1);
        STAGE_H(1, 1, 0, s1);
        MMAQ(0, 1, bg1);
        __builtin_amdgcn_s_barrier();
        READ_AG(0, 1);
        STAGE_H(1, 1, 1, s1);
        MMAQ(1, 0, bg0);
        __builtin_amdgcn_s_barrier();
        STAGE_H(0, 0, 0, s1 + 1);
        MMAQ(1, 1, bg1);
        if (i + 1 < NIT) asm volatile("s_waitcnt vmcnt(2)" ::: "memory");
        else             asm volatile("s_waitcnt vmcnt(0)" ::: "memory");
        __builtin_amdgcn_s_barrier();
        READ_AG(1, 0); READ_BG(1, 0, bg0);
        STAGE_H(0, 0, 1, s1 + 1);
        MMAQ(0, 0, bg0);
        __builtin_amdgcn_s_barrier();
        READ_BG(1, 1, bg1);
        STAGE_H(0, 1, 0, s1 + 1);
        MMAQ(0, 1, bg1);
        __builtin_amdgcn_s_barrier();
        READ_AG(1, 1);
        STAGE_H(0, 1, 1, s1 + 1);
        MMAQ(1, 0, bg0);
        __builtin_amdgcn_s_barrier();
        STAGE_H(1, 0, 0, s1 + 2);
        MMAQ(1, 1, bg1);
    }

    // ---- LDS-bounce epilogue ----
    float* lf = (float*)lds;                       // [64][260] f32
    v4f b4 = *(const v4f*)&bias[nt * 256 + lane * 4];
    const long Cb0 = (long)(mt * 256) * ldc + nt * 256;

    #pragma unroll
    for (int c = 0; c < 4; ++c) {
        __syncthreads();
        if (wm == (c >> 1)) {
            #pragma unroll
            for (int m = 0; m < 4; ++m)
                #pragma unroll
                for (int nh = 0; nh < 2; ++nh)
                    #pragma unroll
                    for (int n = 0; n < 2; ++n)
                        #pragma unroll
                        for (int r = 0; r < 4; ++r)
                            lf[(m * 16 + fq * 4 + r) * 260 + wn * 64 + nh * 32 + n * 16 + fr]
                                = acc[(c & 1) * 4 + m][nh * 2 + n][r];
        }
        __syncthreads();
        #pragma unroll
        for (int rr = 0; rr < 8; ++rr) {
            int row = wid * 8 + rr;
            v4f v = *(const v4f*)&lf[row * 260 + lane * 4];
            v4f o;
            o.x = v.x * scale + b4.x;
            o.y = v.y * scale + b4.y;
            o.z = v.z * scale + b4.z;
            o.w = v.w * scale + b4.w;
            __builtin_nontemporal_store(o,
                (v4f*)&C[Cb0 + (long)(c * 64 + row) * ldc + lane * 4]);
        }
    }
}

// ---------------- causal softmax, writes bf16 probs ----------------
__global__ void k_softmax(const float* __restrict__ S, uint16_t* __restrict__ P)
{
    int t = blockIdx.x, b = blockIdx.y;
    const float* row = S + ((long)b * 1024 + t) * 1024;
    uint16_t* pr = P + ((long)b * 1024 + t) * 1024;
    int limit = (t & ~127) + 128;
    int s0 = threadIdx.x * 4;
    float vals[4] = {0.f, 0.f, 0.f, 0.f};
    if (s0 < limit) {
        float4 vv = *(const float4*)(row + s0);
        vals[0] = vv.x; vals[1] = vv.y; vals[2] = vv.z; vals[3] = vv.w;
    }
    float mx = -1e30f;
    #pragma unroll
    for (int j = 0; j < 4; ++j) if (s0 + j <= t) mx = fmaxf(mx, vals[j]);
    #pragma unroll
    for (int o = 32; o; o >>= 1) mx = fmaxf(mx, __shfl_xor(mx, o));
    __shared__ float red[8];
    int wave = threadIdx.x >> 6, lane = threadIdx.x & 63;
    if (lane == 0) red[wave] = mx;
    __syncthreads();
    mx = fmaxf(fmaxf(red[0], red[1]), fmaxf(red[2], red[3]));
    float e[4]; float sum = 0.f;
    #pragma unroll
    for (int j = 0; j < 4; ++j) { e[j] = (s0 + j <= t) ? __expf(vals[j] - mx) : 0.f; sum += e[j]; }
    #pragma unroll
    for (int o = 32; o; o >>= 1) sum += __shfl_xor(sum, o);
    if (lane == 0) red[4 + wave] = sum;
    __syncthreads();
    sum = red[4] + red[5] + red[6] + red[7];
    float inv = 1.f / sum;
    if (s0 < limit) {
        #pragma unroll
        for (int j = 0; j < 4; ++j) pr[s0 + j] = f2bf(e[j] * inv);
    }
}

// ---------------- layernorm: out = LN(a)*w + bias ----------------
__global__ void k_ln(const float* __restrict__ a,
                     const float* __restrict__ w, const float* __restrict__ bias,
                     float* __restrict__ outf, uint16_t* __restrict__ outb)
{
    int row = blockIdx.x;
    const float* ar = a + (long)row * 768;
    float v[3]; float s1 = 0.f, s2 = 0.f;
    #pragma unroll
    for (int i = 0; i < 3; ++i) {
        int e = threadIdx.x + i * 256;
        v[i] = ar[e];
        s1 += v[i]; s2 += v[i] * v[i];
    }
    #pragma unroll
    for (int o = 32; o; o >>= 1) { s1 += __shfl_xor(s1, o); s2 += __shfl_xor(s2, o); }
    __shared__ float red[8];
    int wave = threadIdx.x >> 6, lane = threadIdx.x & 63;
    if (lane == 0) { red[wave] = s1; red[4 + wave] = s2; }
    __syncthreads();
    s1 = red[0] + red[1] + red[2] + red[3];
    s2 = red[4] + red[5] + red[6] + red[7];
    float mean = s1 * (1.f / 768.f);
    float var  = s2 * (1.f / 768.f) - mean * mean;
    float rstd = rsqrtf(var + 1e-5f);
    #pragma unroll
    for (int i = 0; i < 3; ++i) {
        int e = threadIdx.x + i * 256;
        float o = (v[i] - mean) * rstd * w[e] + bias[e];
        outf[(long)row * 768 + e] = o;
        outb[(long)row * 768 + e] = f2bf(o);
    }
}

// ------- layernorm for FFN2 split-K=4 -------
__global__ void k_ln_ffn2(const float* __restrict__ p, long pstride,
                          const float* __restrict__ b2, const float* __restrict__ h1,
                          const float* __restrict__ w, const float* __restrict__ bias,
                          float* __restrict__ outf, uint16_t* __restrict__ outb)
{
    int row = blockIdx.x;
    long base = (long)row * 768;
    float v[3]; float s1 = 0.f, s2 = 0.f;
    #pragma unroll
    for (int i = 0; i < 3; ++i) {
        int e = threadIdx.x + i * 256;
        float acc = b2[e] + h1[base + e];
        #pragma unroll
        for (int s = 0; s < 4; ++s) acc += p[base + e + s * pstride];
        v[i] = acc;
        s1 += acc; s2 += acc * acc;
    }
    #pragma unroll
    for (int o = 32; o; o >>= 1) { s1 += __shfl_xor(s1, o); s2 += __shfl_xor(s2, o); }
    __shared__ float red[8];
    int wave = threadIdx.x >> 6, lane = threadIdx.x & 63;
    if (lane == 0) { red[wave] = s1; red[4 + wave] = s2; }
    __syncthreads();
    s1 = red[0] + red[1] + red[2] + red[3];
    s2 = red[4] + red[5] + red[6] + red[7];
    float mean = s1 * (1.f / 768.f);
    float var  = s2 * (1.f / 768.f) - mean * mean;
    float rstd = rsqrtf(var + 1e-5f);
    #pragma unroll
    for (int i = 0; i < 3; ++i) {
        int e = threadIdx.x + i * 256;
        float o = (v[i] - mean) * rstd * w[e] + bias[e];
        outf[base + e] = o;
        outb[base + e] = f2bf(o);
    }
}

// ---------------- host ----------------
extern "C" void kernel_launch(void* const* d_in, const int* in_sizes, int n_in,
                              void* d_out, int out_size, void* d_ws, size_t ws_size,
                              hipStream_t stream)
{
    const int*   x       = (const int*)d_in[0];
    const float* tok_emb = (const float*)d_in[1];
    const float* pos_emb = (const float*)d_in[2];
    const float* Wq  = (const float*)d_in[3];
    const float* bq  = (const float*)d_in[4];
    const float* Wk  = (const float*)d_in[5];
    const float* bk  = (const float*)d_in[6];
    const float* Wv  = (const float*)d_in[7];
    const float* bv  = (const float*)d_in[8];
    const float* ln1w = (const float*)d_in[9];
    const float* ln1b = (const float*)d_in[10];
    const float* W1  = (const float*)d_in[11];
    const float* b1  = (const float*)d_in[12];
    const float* W2  = (const float*)d_in[13];
    const float* b2  = (const float*)d_in[14];
    const float* ln2w = (const float*)d_in[15];
    const float* ln2b = (const float*)d_in[16];
    const float* Wo  = (const float*)d_in[17];
    const float* bo  = (const float*)d_in[18];
    float* out = (float*)d_out;
    (void)in_sizes; (void)n_in; (void)out_size;

    char* ws = (char*)d_ws;
    size_t off = 0;
    auto alloc = [&](size_t bytes) -> char* {
        char* p = ws + off;
        off = (off + bytes + 255) & ~(size_t)255;
        return p;
    };
    uint16_t* WoT   = (uint16_t*)alloc(32000L * 768 * 2);
    float*    hf    = (float*)alloc(2048L * 768 * 4);
    uint16_t* hb    = (uint16_t*)alloc(2048L * 768 * 2);
    uint16_t* qkv   = (uint16_t*)alloc(2048L * 2304 * 2);
    uint16_t* vT    = (uint16_t*)alloc(2L * 768 * 1024 * 2);
    float*    sc    = (float*)alloc(2L * 1024 * 1024 * 4);
    uint16_t* pr    = (uint16_t*)alloc(2L * 1024 * 1024 * 2);
    float*    hsum  = (float*)alloc(2048L * 768 * 4);
    float*    h1f   = (float*)alloc(2048L * 768 * 4);
    uint16_t* h1b   = (uint16_t*)alloc(2048L * 768 * 2);
    uint16_t* f1    = (uint16_t*)alloc(2048L * 3072 * 2);
    float*    f2p   = (float*)alloc(4L * 2048 * 768 * 4);
    float*    bqkvA = (float*)alloc(6L * 2304 * 4);
    const long PSTR = 2048L * 768;

    size_t mark = off;
    uint16_t* WqkvTA = (uint16_t*)alloc(6L * 2304 * 768 * 2);
    uint16_t* W1TA   = (uint16_t*)alloc(6L * 3072 * 768 * 2);
    uint16_t* W2TA   = (uint16_t*)alloc(6L * 768 * 3072 * 2);
    bool hoist = (off <= ws_size);
    uint16_t *WqkvT = nullptr, *W1T = nullptr, *W2T = nullptr;
    if (!hoist) {
        off = mark;
        WqkvT = (uint16_t*)alloc(2304L * 768 * 2);
        W1T   = (uint16_t*)alloc(3072L * 768 * 2);
        W2T   = (uint16_t*)alloc(768L * 3072 * 2);
    }

    dim3 tb(32, 8);
    const float iscale = 0.036084391824351615f;  // 1/sqrt(768)
    const long EE = 768L * 768;

    k_transpose<float><<<dim3(1000, 24, 1), tb, 0, stream>>>(Wo, WoT, 32000, 768, 0, 0);
    k_embed<<<2048, 256, 0, stream>>>(x, tok_emb, pos_emb, hf, hb);
    k_concat3<<<dim3(3, 6), 256, 0, stream>>>(bq, bk, bv, bqkvA);

    if (hoist) {
        k_transpose<float><<<dim3(24, 24, 6), tb, 0, stream>>>(Wq, WqkvTA,             768, 768, EE, 2304L*768);
        k_transpose<float><<<dim3(24, 24, 6), tb, 0, stream>>>(Wk, WqkvTA + 768L*768,  768, 768, EE, 2304L*768);
        k_transpose<float><<<dim3(24, 24, 6), tb, 0, stream>>>(Wv, WqkvTA + 1536L*768, 768, 768, EE, 2304L*768);
        k_transpose<float><<<dim3(96, 24, 6), tb, 0, stream>>>(W1, W1TA, 3072, 768, 768L*3072, 3072L*768);
        k_transpose<float><<<dim3(24, 96, 6), tb, 0, stream>>>(W2, W2TA, 768, 3072, 3072L*768, 768L*3072);
    }

    for (int l = 0; l < 6; ++l) {
        uint16_t* WqkvL = hoist ? (WqkvTA + l * 2304L * 768) : WqkvT;
        uint16_t* W1L   = hoist ? (W1TA   + l * 3072L * 768) : W1T;
        uint16_t* W2L   = hoist ? (W2TA   + l * 768L * 3072) : W2T;
        if (!hoist) {
            k_transpose<float><<<dim3(24, 24, 1), tb, 0, stream>>>(Wq + l * EE, WqkvT,             768, 768, 0, 0);
            k_transpose<float><<<dim3(24, 24, 1), tb, 0, stream>>>(Wk + l * EE, WqkvT + 768L*768,  768, 768, 0, 0);
            k_transpose<float><<<dim3(24, 24, 1), tb, 0, stream>>>(Wv + l * EE, WqkvT + 1536L*768, 768, 768, 0, 0);
            k_transpose<float><<<dim3(96, 24, 1), tb, 0, stream>>>(W1 + l * 768L * 3072, W1T, 3072, 768, 0, 0);
            k_transpose<float><<<dim3(24, 96, 1), tb, 0, stream>>>(W2 + l * 3072L * 768, W2T, 768, 3072, 0, 0);
        }

        // qkv = h @ [Wq|Wk|Wv] + bias; V third written directly transposed to vT
        k_gemmp<uint16_t, true, false, false, true><<<dim3(36, 16, 1), 256, 0, stream>>>(
            hb, WqkvL, qkv, bqkvA + l * 2304, nullptr, vT,
            768, 768, 768, 2304, 0, 0, 0, 1.f, 0);
        // scores = Q @ K^T / sqrt(E), causal tile-skip   (144 active)
        k_gemmp<float, false, false, false, false><<<dim3(16, 8, 2), 256, 0, stream>>>(
            qkv, qkv + 768, sc, nullptr, nullptr, nullptr, 768, 2304, 2304, 1024,
            1024L * 2304, 1024L * 2304, 1024L * 1024, iscale, 1);
        k_softmax<<<dim3(1024, 2), 256, 0, stream>>>(sc, pr);
        // hsum = P @ V + h   (K clamped causally)   (192 blocks)
        k_gemmp<float, false, false, true, false><<<dim3(12, 8, 2), 256, 0, stream>>>(
            pr, vT, hsum, nullptr, hf, nullptr, 1024, 1024, 1024, 768,
            1024L * 1024, 768L * 1024, 1024L * 768, 1.f, 2);
        k_ln<<<2048, 256, 0, stream>>>(hsum, ln1w + l * 768, ln1b + l * 768, h1f, h1b);
        // f1 = relu(h1 @ W1 + b1)   (768 blocks)
        k_gemmp<uint16_t, true, true, false, false><<<dim3(48, 16, 1), 256, 0, stream>>>(
            h1b, W1L, f1, b1 + l * 3072, nullptr, nullptr, 768, 768, 768, 3072, 0, 0, 0, 1.f, 0);
        // FFN2 split-K=4   (768 blocks)
        k_gemmp<float, false, false, false, false><<<dim3(12, 16, 4), 256, 0, stream>>>(
            f1, W2L, f2p, nullptr, nullptr, nullptr, 768, 3072, 3072, 768,
            768, 768, PSTR, 1.f, 0);
        k_ln_ffn2<<<2048, 256, 0, stream>>>(f2p, PSTR, b2 + l * 768, h1f,
                                            ln2w + l * 768, ln2b + l * 768, hf, hb);
    }

    // logits = h @ Wo + bo -> f32 [2048, 32000]  (256x256, 8-phase, 1000 blocks)
    k_glogits<<<dim3(125, 8, 1), 512, 0, stream>>>(
        hb, WoT, out, bo, 768, 768, 768, 32000, 1.f);
}

// Round 19
// 776.330 us; speedup vs baseline: 1.1181x; 1.1181x over previous
//
#include <hip/hip_runtime.h>
#include <stdint.h>

// ---------------- types & helpers ----------------
typedef __bf16 v8bf __attribute__((ext_vector_type(8)));
typedef float  v4f  __attribute__((ext_vector_type(4)));

__device__ __forceinline__ float bf2f(uint16_t h) {
    union { uint32_t u; float f; } x; x.u = ((uint32_t)h) << 16; return x.f;
}
__device__ __forceinline__ uint16_t f2bf(float f) {
    union { float f; uint32_t u; } x; x.f = f;
    uint32_t r = x.u + 0x7fffu + ((x.u >> 16) & 1u);
    return (uint16_t)(r >> 16);
}

__device__ __forceinline__ void gload16(const uint16_t* g, uint16_t* l) {
    __builtin_amdgcn_global_load_lds((const __attribute__((address_space(1))) void*)g,
                                     (__attribute__((address_space(3))) void*)l, 16, 0, 0);
}

// ---------------- embed ----------------
__global__ void k_embed(const int* __restrict__ x, const float* __restrict__ tok,
                        const float* __restrict__ pos, float* __restrict__ hf,
                        uint16_t* __restrict__ hb)
{
    int i = blockIdx.x;
    int t = i & 1023;
    int tk = x[i];
    const float* te = tok + (long)tk * 768;
    const float* pe = pos + (long)t * 768;
    for (int j = threadIdx.x; j < 768; j += 256) {
        float v = te[j] + pe[j];
        hf[(long)i * 768 + j] = v;
        hb[(long)i * 768 + j] = f2bf(v);
    }
}

// ---------------- transpose + cast to bf16 ----------------
template<typename SrcT>
__global__ void k_transpose(const SrcT* __restrict__ src, uint16_t* __restrict__ dst,
                            int ldS, int ldD, long sBatch, long dBatch)
{
    __shared__ float tile[32][33];
    src += (long)blockIdx.z * sBatch;
    dst += (long)blockIdx.z * dBatch;
    int c0 = blockIdx.x * 32, r0 = blockIdx.y * 32;
    int tx = threadIdx.x, ty = threadIdx.y;
    #pragma unroll
    for (int i = 0; i < 4; ++i) {
        int r = r0 + ty + i * 8;
        SrcT s = src[(long)r * ldS + c0 + tx];
        float v;
        if constexpr (sizeof(SrcT) == 4) v = (float)s; else v = bf2f((uint16_t)s);
        tile[ty + i * 8][tx] = v;
    }
    __syncthreads();
    #pragma unroll
    for (int i = 0; i < 4; ++i) {
        int c = c0 + ty + i * 8;
        dst[(long)c * ldD + r0 + tx] = f2bf(tile[tx][ty + i * 8]);
    }
}

// ---------------- concat qkv biases: grid (3, L) ----------------
__global__ void k_concat3(const float* __restrict__ a, const float* __restrict__ b,
                          const float* __restrict__ c, float* __restrict__ out)
{
    int l = blockIdx.y;
    const float* s = (blockIdx.x == 0) ? a : ((blockIdx.x == 1) ? b : c);
    s += (long)l * 768;
    for (int j = threadIdx.x; j < 768; j += 256)
        out[(long)l * 2304 + blockIdx.x * 768 + j] = s[j];
}

// ==== layer GEMM: 128x64 tile, BK=64, ring-2, conflict-free swizzle (R9/R17) ====
// R19: reverted to R17 exactly. R18's single-buffer @6 blocks/CU regressed 90 µs:
// with serial stage->vmcnt(0)->compute, co-resident blocks stall synchronously and
// HBM latency lands on every block's critical path. Ring-2's stage-ahead removes it.
// For short-K latency-bound GEMMs: prefetch depth > occupancy.
template<typename OutT, bool BIAS, bool RELU, bool RES, bool VOUT>
__global__ __launch_bounds__(256, 3)
void k_gemmp(const uint16_t* __restrict__ A, const uint16_t* __restrict__ BT,
             OutT* __restrict__ C, const float* __restrict__ bias,
             const float* __restrict__ res, uint16_t* __restrict__ vout,
             int K, int lda, int ldb, int ldc,
             long bsA, long bsB, long bsC, float scale, int causal)
{
    const int nwg = gridDim.x * gridDim.y;
    int lin = blockIdx.y * gridDim.x + blockIdx.x;
    {
        int q = nwg >> 3, r = nwg & 7, x = lin & 7, i = lin >> 3;
        lin = (x < r ? x * (q + 1) : r * (q + 1) + (x - r) * q) + i;
    }
    const int mt = lin % gridDim.y;
    const int nt = lin / gridDim.y;

    if (causal == 1 && nt * 64 >= (mt + 1) * 128) return;
    const int Keff = (causal == 2) ? ((mt + 1) * 128 < K ? (mt + 1) * 128 : K) : K;
    const int KT = Keff >> 6;

    __shared__ uint16_t lds[2][192 * 64];
    const int tid  = threadIdx.x;
    const int lane = tid & 63;
    const int bz   = blockIdx.z;
    const uint16_t* Ab = A + (long)bz * bsA + (long)mt * 128 * lda;
    const uint16_t* Bb = BT + (long)bz * bsB + (long)nt * 64 * ldb;

    const int wm = (tid >> 6) >> 1, wn = (tid >> 6) & 1;
    const int fr = lane & 15, fq = lane >> 4;

    const int srow = tid >> 3;
    const int sl   = tid & 7;

    v4f acc[4][2];
    #pragma unroll
    for (int m = 0; m < 4; ++m)
        #pragma unroll
        for (int n = 0; n < 2; ++n) acc[m][n] = (v4f){0.f, 0.f, 0.f, 0.f};

    auto stage = [&](int t, int buf) {
        const int ko = t * 64;
        #pragma unroll
        for (int p = 0; p < 6; ++p) {
            int row = p * 32 + srow;
            int ss  = (sl ^ (row & 7)) * 8;
            const uint16_t* g = (p < 4) ? (Ab + (long)row * lda + ko + ss)
                                        : (Bb + (long)(row - 128) * ldb + ko + ss);
            gload16(g, &lds[buf][p * 2048 + tid * 8]);
        }
    };

    stage(0, 0);

    for (int kti = 0; kti < KT; ++kti) {
        asm volatile("s_waitcnt vmcnt(0)" ::: "memory");
        __builtin_amdgcn_s_barrier();
        if (kti + 1 < KT) stage(kti + 1, (kti + 1) & 1);

        const uint16_t* l = &lds[kti & 1][0];
        #pragma unroll
        for (int kk = 0; kk < 2; ++kk) {
            const int sIdx = kk * 4 + fq;
            v8bf ag[4], bg[2];
            #pragma unroll
            for (int m = 0; m < 4; ++m) {
                int r = wm * 64 + m * 16 + fr;
                ag[m] = *(const v8bf*)&l[r * 64 + ((sIdx ^ (r & 7)) << 3)];
            }
            #pragma unroll
            for (int n = 0; n < 2; ++n) {
                int r = 128 + wn * 32 + n * 16 + fr;
                bg[n] = *(const v8bf*)&l[r * 64 + ((sIdx ^ (r & 7)) << 3)];
            }
            __builtin_amdgcn_s_setprio(1);
            #pragma unroll
            for (int m = 0; m < 4; ++m)
                #pragma unroll
                for (int n = 0; n < 2; ++n)
                    acc[m][n] = __builtin_amdgcn_mfma_f32_16x16x32_bf16(ag[m], bg[n], acc[m][n], 0, 0, 0);
            __builtin_amdgcn_s_setprio(0);
        }
    }

    if (VOUT && nt >= 24) {
        // V region of qkv: write transposed to vout[b][d][s]; b=row>>10, s=row&1023
        #pragma unroll
        for (int n = 0; n < 2; ++n) {
            int col = wn * 32 + n * 16 + fr;
            float bv = BIAS ? bias[nt * 64 + col] : 0.f;
            int d = nt * 64 + col - 1536;      // 0..767
            #pragma unroll
            for (int m = 0; m < 4; ++m) {
                int grow = mt * 128 + wm * 64 + m * 16 + fq * 4;   // multiple of 4
                union { uint16_t u[4]; unsigned long long ll; } t4;
                #pragma unroll
                for (int r = 0; r < 4; ++r) t4.u[r] = f2bf(acc[m][n][r] * scale + bv);
                *(unsigned long long*)&vout[((long)(grow >> 10) * 768 + d) * 1024 + (grow & 1023)] = t4.ll;
            }
        }
        return;
    }

    OutT* Cb = C + (long)bz * bsC + (long)mt * 128 * ldc + nt * 64;
    const float* Rb = RES ? (res + (long)bz * bsC + (long)mt * 128 * ldc + nt * 64) : nullptr;
    #pragma unroll
    for (int n = 0; n < 2; ++n) {
        int col = wn * 32 + n * 16 + fr;
        float bv = BIAS ? bias[nt * 64 + col] : 0.f;
        #pragma unroll
        for (int m = 0; m < 4; ++m) {
            #pragma unroll
            for (int r = 0; r < 4; ++r) {
                int row = wm * 64 + m * 16 + fq * 4 + r;
                float v = acc[m][n][r] * scale + bv;
                if (RES) v += Rb[(long)row * ldc + col];
                if (RELU) v = fmaxf(v, 0.f);
                if constexpr (sizeof(OutT) == 4) Cb[(long)row * ldc + col] = v;
                else                             Cb[(long)row * ldc + col] = f2bf(v);
            }
        }
    }
}

// ==== logits GEMM: 256x256, BK=64, 8-phase counted-vmcnt (R16, verified) ====
#define STAGE_H(buf, op, half, s)                                                   \
    do { if ((s) < KS) {                                                            \
        const uint16_t* Gp_ = (op) ? Bb : Ab;                                       \
        const int ldg_ = (op) ? ldb : lda;                                          \
        uint16_t* dst_ = &lds[buf][(op) * 16384 + (half) * 8192];                   \
        { int rg_ = (half) * 128 + (tid >> 3);                                      \
          int ss_ = ((tid & 7) ^ (rg_ & 7)) << 3;                                   \
          gload16(Gp_ + (long)rg_ * ldg_ + (s) * 64 + ss_, dst_ + tid * 8); }       \
        { int rg_ = (half) * 128 + (tid >> 3) + 64;                                 \
          int ss_ = ((tid & 7) ^ (rg_ & 7)) << 3;                                   \
          gload16(Gp_ + (long)rg_ * ldg_ + (s) * 64 + ss_, dst_ + (tid + 512) * 8); } \
    } } while (0)

#define READ_AG(buf, mh)                                                            \
    do { _Pragma("unroll") for (int m_ = 0; m_ < 4; ++m_) {                         \
        int r_ = wm * 128 + (mh) * 64 + m_ * 16 + fr;                               \
        ag[m_][0] = *(const v8bf*)&lds[buf][r_ * 64 + ((fq ^ (r_ & 7)) << 3)];      \
        ag[m_][1] = *(const v8bf*)&lds[buf][r_ * 64 + (((4 | fq) ^ (r_ & 7)) << 3)];\
    } } while (0)

#define READ_BG(buf, nh, BG)                                                        \
    do { _Pragma("unroll") for (int n_ = 0; n_ < 2; ++n_) {                         \
        int r_ = wn * 64 + (nh) * 32 + n_ * 16 + fr;                                \
        BG[n_][0] = *(const v8bf*)&lds[buf][16384 + r_ * 64 + ((fq ^ (r_ & 7)) << 3)]; \
        BG[n_][1] = *(const v8bf*)&lds[buf][16384 + r_ * 64 + (((4 | fq) ^ (r_ & 7)) << 3)]; \
    } } while (0)

#define MMAQ(mh, nh, BG)                                                            \
    do { __builtin_amdgcn_s_setprio(1);                                             \
        _Pragma("unroll") for (int m_ = 0; m_ < 4; ++m_)                            \
        _Pragma("unroll") for (int n_ = 0; n_ < 2; ++n_) {                          \
            acc[(mh)*4+m_][(nh)*2+n_] = __builtin_amdgcn_mfma_f32_16x16x32_bf16(    \
                ag[m_][0], BG[n_][0], acc[(mh)*4+m_][(nh)*2+n_], 0, 0, 0);          \
            acc[(mh)*4+m_][(nh)*2+n_] = __builtin_amdgcn_mfma_f32_16x16x32_bf16(    \
                ag[m_][1], BG[n_][1], acc[(mh)*4+m_][(nh)*2+n_], 0, 0, 0);          \
        }                                                                           \
        __builtin_amdgcn_s_setprio(0);                                              \
    } while (0)

__global__ __launch_bounds__(512, 2)
void k_glogits(const uint16_t* __restrict__ A, const uint16_t* __restrict__ BT,
               float* __restrict__ C, const float* __restrict__ bias,
               int K, int lda, int ldb, int ldc, float scale)
{
    __shared__ uint16_t lds[2][32768];   // [buf][A 256x64 | B 256x64] = 128 KiB

    const int nwg = gridDim.x * gridDim.y;
    int lin = blockIdx.y * gridDim.x + blockIdx.x;
    {
        int q = nwg >> 3, r = nwg & 7, x = lin & 7, i = lin >> 3;
        lin = (x < r ? x * (q + 1) : r * (q + 1) + (x - r) * q) + i;
    }
    const int nt = lin % gridDim.x;   // 125 n-tiles (n-fastest within XCD chunk)
    const int mt = lin / gridDim.x;   // 8 m-bands (one per XCD chunk)

    const int tid  = threadIdx.x;
    const int lane = tid & 63;
    const int wid  = tid >> 6;
    const int wm = wid >> 2, wn = wid & 3;       // 2M x 4N -> 128x64 per wave
    const int fr = lane & 15, fq = lane >> 4;

    const uint16_t* Ab = A  + (long)mt * 256 * lda;
    const uint16_t* Bb = BT + (long)nt * 256 * ldb;

    const int KS  = K >> 6;        // 12 K-steps
    const int NIT = KS >> 1;       // 6 iterations

    v4f acc[8][4];
    #pragma unroll
    for (int m = 0; m < 8; ++m)
        #pragma unroll
        for (int n = 0; n < 4; ++n) acc[m][n] = (v4f){0.f, 0.f, 0.f, 0.f};

    v8bf ag[4][2], bg0[2][2], bg1[2][2];

    STAGE_H(0, 0, 0, 0);
    STAGE_H(0, 0, 1, 0);
    STAGE_H(0, 1, 0, 0);
    STAGE_H(0, 1, 1, 0);
    STAGE_H(1, 0, 0, 1);

    for (int i = 0; i < NIT; ++i) {
        const int s1 = 2 * i + 1;
        asm volatile("s_waitcnt vmcnt(2)" ::: "memory");
        __builtin_amdgcn_s_barrier();
        READ_AG(0, 0); READ_BG(0, 0, bg0);
        STAGE_H(1, 0, 1, s1);
        MMAQ(0, 0, bg0);
        __builtin_amdgcn_s_barrier();
        READ_BG(0, 1, bg1);
        STAGE_H(1, 1, 0, s1);
        MMAQ(0, 1, bg1);
        __builtin_amdgcn_s_barrier();
        READ_AG(0, 1);
        STAGE_H(1, 1, 1, s1);
        MMAQ(1, 0, bg0);
        __builtin_amdgcn_s_barrier();
        STAGE_H(0, 0, 0, s1 + 1);
        MMAQ(1, 1, bg1);
        if (i + 1 < NIT) asm volatile("s_waitcnt vmcnt(2)" ::: "memory");
        else             asm volatile("s_waitcnt vmcnt(0)" ::: "memory");
        __builtin_amdgcn_s_barrier();
        READ_AG(1, 0); READ_BG(1, 0, bg0);
        STAGE_H(0, 0, 1, s1 + 1);
        MMAQ(0, 0, bg0);
        __builtin_amdgcn_s_barrier();
        READ_BG(1, 1, bg1);
        STAGE_H(0, 1, 0, s1 + 1);
        MMAQ(0, 1, bg1);
        __builtin_amdgcn_s_barrier();
        READ_AG(1, 1);
        STAGE_H(0, 1, 1, s1 + 1);
        MMAQ(1, 0, bg0);
        __builtin_amdgcn_s_barrier();
        STAGE_H(1, 0, 0, s1 + 2);
        MMAQ(1, 1, bg1);
    }

    // ---- LDS-bounce epilogue ----
    float* lf = (float*)lds;                       // [64][260] f32
    v4f b4 = *(const v4f*)&bias[nt * 256 + lane * 4];
    const long Cb0 = (long)(mt * 256) * ldc + nt * 256;

    #pragma unroll
    for (int c = 0; c < 4; ++c) {
        __syncthreads();
        if (wm == (c >> 1)) {
            #pragma unroll
            for (int m = 0; m < 4; ++m)
                #pragma unroll
                for (int nh = 0; nh < 2; ++nh)
                    #pragma unroll
                    for (int n = 0; n < 2; ++n)
                        #pragma unroll
                        for (int r = 0; r < 4; ++r)
                            lf[(m * 16 + fq * 4 + r) * 260 + wn * 64 + nh * 32 + n * 16 + fr]
                                = acc[(c & 1) * 4 + m][nh * 2 + n][r];
        }
        __syncthreads();
        #pragma unroll
        for (int rr = 0; rr < 8; ++rr) {
            int row = wid * 8 + rr;
            v4f v = *(const v4f*)&lf[row * 260 + lane * 4];
            v4f o;
            o.x = v.x * scale + b4.x;
            o.y = v.y * scale + b4.y;
            o.z = v.z * scale + b4.z;
            o.w = v.w * scale + b4.w;
            __builtin_nontemporal_store(o,
                (v4f*)&C[Cb0 + (long)(c * 64 + row) * ldc + lane * 4]);
        }
    }
}

// ---------------- causal softmax, writes bf16 probs ----------------
__global__ void k_softmax(const float* __restrict__ S, uint16_t* __restrict__ P)
{
    int t = blockIdx.x, b = blockIdx.y;
    const float* row = S + ((long)b * 1024 + t) * 1024;
    uint16_t* pr = P + ((long)b * 1024 + t) * 1024;
    int limit = (t & ~127) + 128;
    int s0 = threadIdx.x * 4;
    float vals[4] = {0.f, 0.f, 0.f, 0.f};
    if (s0 < limit) {
        float4 vv = *(const float4*)(row + s0);
        vals[0] = vv.x; vals[1] = vv.y; vals[2] = vv.z; vals[3] = vv.w;
    }
    float mx = -1e30f;
    #pragma unroll
    for (int j = 0; j < 4; ++j) if (s0 + j <= t) mx = fmaxf(mx, vals[j]);
    #pragma unroll
    for (int o = 32; o; o >>= 1) mx = fmaxf(mx, __shfl_xor(mx, o));
    __shared__ float red[8];
    int wave = threadIdx.x >> 6, lane = threadIdx.x & 63;
    if (lane == 0) red[wave] = mx;
    __syncthreads();
    mx = fmaxf(fmaxf(red[0], red[1]), fmaxf(red[2], red[3]));
    float e[4]; float sum = 0.f;
    #pragma unroll
    for (int j = 0; j < 4; ++j) { e[j] = (s0 + j <= t) ? __expf(vals[j] - mx) : 0.f; sum += e[j]; }
    #pragma unroll
    for (int o = 32; o; o >>= 1) sum += __shfl_xor(sum, o);
    if (lane == 0) red[4 + wave] = sum;
    __syncthreads();
    sum = red[4] + red[5] + red[6] + red[7];
    float inv = 1.f / sum;
    if (s0 < limit) {
        #pragma unroll
        for (int j = 0; j < 4; ++j) pr[s0 + j] = f2bf(e[j] * inv);
    }
}

// ---------------- layernorm: out = LN(a)*w + bias ----------------
__global__ void k_ln(const float* __restrict__ a,
                     const float* __restrict__ w, const float* __restrict__ bias,
                     float* __restrict__ outf, uint16_t* __restrict__ outb)
{
    int row = blockIdx.x;
    const float* ar = a + (long)row * 768;
    float v[3]; float s1 = 0.f, s2 = 0.f;
    #pragma unroll
    for (int i = 0; i < 3; ++i) {
        int e = threadIdx.x + i * 256;
        v[i] = ar[e];
        s1 += v[i]; s2 += v[i] * v[i];
    }
    #pragma unroll
    for (int o = 32; o; o >>= 1) { s1 += __shfl_xor(s1, o); s2 += __shfl_xor(s2, o); }
    __shared__ float red[8];
    int wave = threadIdx.x >> 6, lane = threadIdx.x & 63;
    if (lane == 0) { red[wave] = s1; red[4 + wave] = s2; }
    __syncthreads();
    s1 = red[0] + red[1] + red[2] + red[3];
    s2 = red[4] + red[5] + red[6] + red[7];
    float mean = s1 * (1.f / 768.f);
    float var  = s2 * (1.f / 768.f) - mean * mean;
    float rstd = rsqrtf(var + 1e-5f);
    #pragma unroll
    for (int i = 0; i < 3; ++i) {
        int e = threadIdx.x + i * 256;
        float o = (v[i] - mean) * rstd * w[e] + bias[e];
        outf[(long)row * 768 + e] = o;
        outb[(long)row * 768 + e] = f2bf(o);
    }
}

// ------- layernorm for FFN2 split-K=4 -------
__global__ void k_ln_ffn2(const float* __restrict__ p, long pstride,
                          const float* __restrict__ b2, const float* __restrict__ h1,
                          const float* __restrict__ w, const float* __restrict__ bias,
                          float* __restrict__ outf, uint16_t* __restrict__ outb)
{
    int row = blockIdx.x;
    long base = (long)row * 768;
    float v[3]; float s1 = 0.f, s2 = 0.f;
    #pragma unroll
    for (int i = 0; i < 3; ++i) {
        int e = threadIdx.x + i * 256;
        float acc = b2[e] + h1[base + e];
        #pragma unroll
        for (int s = 0; s < 4; ++s) acc += p[base + e + s * pstride];
        v[i] = acc;
        s1 += acc; s2 += acc * acc;
    }
    #pragma unroll
    for (int o = 32; o; o >>= 1) { s1 += __shfl_xor(s1, o); s2 += __shfl_xor(s2, o); }
    __shared__ float red[8];
    int wave = threadIdx.x >> 6, lane = threadIdx.x & 63;
    if (lane == 0) { red[wave] = s1; red[4 + wave] = s2; }
    __syncthreads();
    s1 = red[0] + red[1] + red[2] + red[3];
    s2 = red[4] + red[5] + red[6] + red[7];
    float mean = s1 * (1.f / 768.f);
    float var  = s2 * (1.f / 768.f) - mean * mean;
    float rstd = rsqrtf(var + 1e-5f);
    #pragma unroll
    for (int i = 0; i < 3; ++i) {
        int e = threadIdx.x + i * 256;
        float o = (v[i] - mean) * rstd * w[e] + bias[e];
        outf[base + e] = o;
        outb[base + e] = f2bf(o);
    }
}

// ---------------- host ----------------
extern "C" void kernel_launch(void* const* d_in, const int* in_sizes, int n_in,
                              void* d_out, int out_size, void* d_ws, size_t ws_size,
                              hipStream_t stream)
{
    const int*   x       = (const int*)d_in[0];
    const float* tok_emb = (const float*)d_in[1];
    const float* pos_emb = (const float*)d_in[2];
    const float* Wq  = (const float*)d_in[3];
    const float* bq  = (const float*)d_in[4];
    const float* Wk  = (const float*)d_in[5];
    const float* bk  = (const float*)d_in[6];
    const float* Wv  = (const float*)d_in[7];
    const float* bv  = (const float*)d_in[8];
    const float* ln1w = (const float*)d_in[9];
    const float* ln1b = (const float*)d_in[10];
    const float* W1  = (const float*)d_in[11];
    const float* b1  = (const float*)d_in[12];
    const float* W2  = (const float*)d_in[13];
    const float* b2  = (const float*)d_in[14];
    const float* ln2w = (const float*)d_in[15];
    const float* ln2b = (const float*)d_in[16];
    const float* Wo  = (const float*)d_in[17];
    const float* bo  = (const float*)d_in[18];
    float* out = (float*)d_out;
    (void)in_sizes; (void)n_in; (void)out_size;

    char* ws = (char*)d_ws;
    size_t off = 0;
    auto alloc = [&](size_t bytes) -> char* {
        char* p = ws + off;
        off = (off + bytes + 255) & ~(size_t)255;
        return p;
    };
    uint16_t* WoT   = (uint16_t*)alloc(32000L * 768 * 2);
    float*    hf    = (float*)alloc(2048L * 768 * 4);
    uint16_t* hb    = (uint16_t*)alloc(2048L * 768 * 2);
    uint16_t* qkv   = (uint16_t*)alloc(2048L * 2304 * 2);
    uint16_t* vT    = (uint16_t*)alloc(2L * 768 * 1024 * 2);
    float*    sc    = (float*)alloc(2L * 1024 * 1024 * 4);
    uint16_t* pr    = (uint16_t*)alloc(2L * 1024 * 1024 * 2);
    float*    hsum  = (float*)alloc(2048L * 768 * 4);
    float*    h1f   = (float*)alloc(2048L * 768 * 4);
    uint16_t* h1b   = (uint16_t*)alloc(2048L * 768 * 2);
    uint16_t* f1    = (uint16_t*)alloc(2048L * 3072 * 2);
    float*    f2p   = (float*)alloc(4L * 2048 * 768 * 4);
    float*    bqkvA = (float*)alloc(6L * 2304 * 4);
    const long PSTR = 2048L * 768;

    size_t mark = off;
    uint16_t* WqkvTA = (uint16_t*)alloc(6L * 2304 * 768 * 2);
    uint16_t* W1TA   = (uint16_t*)alloc(6L * 3072 * 768 * 2);
    uint16_t* W2TA   = (uint16_t*)alloc(6L * 768 * 3072 * 2);
    bool hoist = (off <= ws_size);
    uint16_t *WqkvT = nullptr, *W1T = nullptr, *W2T = nullptr;
    if (!hoist) {
        off = mark;
        WqkvT = (uint16_t*)alloc(2304L * 768 * 2);
        W1T   = (uint16_t*)alloc(3072L * 768 * 2);
        W2T   = (uint16_t*)alloc(768L * 3072 * 2);
    }

    dim3 tb(32, 8);
    const float iscale = 0.036084391824351615f;  // 1/sqrt(768)
    const long EE = 768L * 768;

    k_transpose<float><<<dim3(1000, 24, 1), tb, 0, stream>>>(Wo, WoT, 32000, 768, 0, 0);
    k_embed<<<2048, 256, 0, stream>>>(x, tok_emb, pos_emb, hf, hb);
    k_concat3<<<dim3(3, 6), 256, 0, stream>>>(bq, bk, bv, bqkvA);

    if (hoist) {
        k_transpose<float><<<dim3(24, 24, 6), tb, 0, stream>>>(Wq, WqkvTA,             768, 768, EE, 2304L*768);
        k_transpose<float><<<dim3(24, 24, 6), tb, 0, stream>>>(Wk, WqkvTA + 768L*768,  768, 768, EE, 2304L*768);
        k_transpose<float><<<dim3(24, 24, 6), tb, 0, stream>>>(Wv, WqkvTA + 1536L*768, 768, 768, EE, 2304L*768);
        k_transpose<float><<<dim3(96, 24, 6), tb, 0, stream>>>(W1, W1TA, 3072, 768, 768L*3072, 3072L*768);
        k_transpose<float><<<dim3(24, 96, 6), tb, 0, stream>>>(W2, W2TA, 768, 3072, 3072L*768, 768L*3072);
    }

    for (int l = 0; l < 6; ++l) {
        uint16_t* WqkvL = hoist ? (WqkvTA + l * 2304L * 768) : WqkvT;
        uint16_t* W1L   = hoist ? (W1TA   + l * 3072L * 768) : W1T;
        uint16_t* W2L   = hoist ? (W2TA   + l * 768L * 3072) : W2T;
        if (!hoist) {
            k_transpose<float><<<dim3(24, 24, 1), tb, 0, stream>>>(Wq + l * EE, WqkvT,             768, 768, 0, 0);
            k_transpose<float><<<dim3(24, 24, 1), tb, 0, stream>>>(Wk + l * EE, WqkvT + 768L*768,  768, 768, 0, 0);
            k_transpose<float><<<dim3(24, 24, 1), tb, 0, stream>>>(Wv + l * EE, WqkvT + 1536L*768, 768, 768, 0, 0);
            k_transpose<float><<<dim3(96, 24, 1), tb, 0, stream>>>(W1 + l * 768L * 3072, W1T, 3072, 768, 0, 0);
            k_transpose<float><<<dim3(24, 96, 1), tb, 0, stream>>>(W2 + l * 3072L * 768, W2T, 768, 3072, 0, 0);
        }

        // qkv = h @ [Wq|Wk|Wv] + bias; V third written directly transposed to vT
        k_gemmp<uint16_t, true, false, false, true><<<dim3(36, 16, 1), 256, 0, stream>>>(
            hb, WqkvL, qkv, bqkvA + l * 2304, nullptr, vT,
            768, 768, 768, 2304, 0, 0, 0, 1.f, 0);
        // scores = Q @ K^T / sqrt(E), causal tile-skip   (144 active)
        k_gemmp<float, false, false, false, false><<<dim3(16, 8, 2), 256, 0, stream>>>(
            qkv, qkv + 768, sc, nullptr, nullptr, nullptr, 768, 2304, 2304, 1024,
            1024L * 2304, 1024L * 2304, 1024L * 1024, iscale, 1);
        k_softmax<<<dim3(1024, 2), 256, 0, stream>>>(sc, pr);
        // hsum = P @ V + h   (K clamped causally)   (192 blocks)
        k_gemmp<float, false, false, true, false><<<dim3(12, 8, 2), 256, 0, stream>>>(
            pr, vT, hsum, nullptr, hf, nullptr, 1024, 1024, 1024, 768,
            1024L * 1024, 768L * 1024, 1024L * 768, 1.f, 2);
        k_ln<<<2048, 256, 0, stream>>>(hsum, ln1w + l * 768, ln1b + l * 768, h1f, h1b);
        // f1 = relu(h1 @ W1 + b1)   (768 blocks)
        k_gemmp<uint16_t, true, true, false, false><<<dim3(48, 16, 1), 256, 0, stream>>>(
            h1b, W1L, f1, b1 + l * 3072, nullptr, nullptr, 768, 768, 768, 3072, 0, 0, 0, 1.f, 0);
        // FFN2 split-K=4   (768 blocks)
        k_gemmp<float, false, false, false, false><<<dim3(12, 16, 4), 256, 0, stream>>>(
            f1, W2L, f2p, nullptr, nullptr, nullptr, 768, 3072, 3072, 768,
            768, 768, PSTR, 1.f, 0);
        k_ln_ffn2<<<2048, 256, 0, stream>>>(f2p, PSTR, b2 + l * 768, h1f,
                                            ln2w + l * 768, ln2b + l * 768, hf, hb);
    }

    // logits = h @ Wo + bo -> f32 [2048, 32000]  (256x256, 8-phase, 1000 blocks)
    k_glogits<<<dim3(125, 8, 1), 512, 0, stream>>>(
        hb, WoT, out, bo, 768, 768, 768, 32000, 1.f);
}